// Round 9
// baseline (398.861 us; speedup 1.0000x reference)
//
#include <hip/hip_runtime.h>
#include <hip/hip_bf16.h>

#define S_LEN 2048
#define DK 128
#define DV 128
#define BN 64     // KV rows per ws tile (2 subtiles of 32)
#define NT 32     // KV 64-tiles per batch
#define TILE_B 16384                        // bytes per 64x128 bf16 tile
#define VWS_OFF ((size_t)16 * NT * TILE_B)  // 8.39 MB
#define WS_NEED ((size_t)2 * 16 * NT * TILE_B)
// split-KV partial buffers
#define PART_OFF WS_NEED                              // h=1 acc partial, 16.78 MB
#define PART_B   ((size_t)16 * S_LEN * DV * 4)
#define L0_OFF   (PART_OFF + PART_B)                  // l partials, 128 KB each
#define L1_OFF   (L0_OFF + (size_t)16 * S_LEN * 4)
#define WS_NEED_SPLIT (L1_OFF + (size_t)16 * S_LEN * 4)

typedef __attribute__((ext_vector_type(8))) short s16x8;
typedef __attribute__((ext_vector_type(4))) short s16x4;
typedef __attribute__((ext_vector_type(8))) __bf16 bf16x8;
typedef __attribute__((ext_vector_type(4))) float f32x4;
typedef __attribute__((ext_vector_type(16))) float f32x16;
typedef __attribute__((ext_vector_type(4))) unsigned u32x4;

__device__ __forceinline__ short f2bf(float f) {
  unsigned u = __builtin_bit_cast(unsigned, f);
  u += 0x7FFFu + ((u >> 16) & 1u);
  return (short)(u >> 16);
}
__device__ __forceinline__ bf16x8 lds8(const short* p) {
  return __builtin_bit_cast(bf16x8, *(const s16x8*)p);
}
__device__ __forceinline__ bf16x8 gload8v(const char* p) {
  return __builtin_bit_cast(bf16x8, *(const s16x8*)p);
}
// packed f32x2 -> bf16x2 (RNE): low = a, high = b
__device__ __forceinline__ unsigned cvtpk(float a, float b) {
  unsigned r;
  asm("v_cvt_pk_bf16_f32 %0, %1, %2" : "=v"(r) : "v"(a), "v"(b));
  return r;
}
// v_permlane32_swap_b32: a'[l] = l<32 ? a[l] : b[l-32];
//                        b'[l] = l<32 ? a[l+32] : b[l]
__device__ __forceinline__ void plswap(unsigned& a, unsigned& b) {
  asm volatile("s_nop 1\n\tv_permlane32_swap_b32 %0, %1" : "+v"(a), "+v"(b));
}

// ---------------------------------------------------------------------------
// Pass 1: convert K -> bf16, V -> bf16-transposed, FRAGMENT-MAJOR (R7):
// per 32-kv subtile (8192 B), lane ln's 16B chunk for fragment f lives at
// subtile*8192 + f*1024 + ln*16 -> every main-kernel frag load is one
// contiguous 128B-aligned 1KB block (8 cache lines, minimum).
//   K chunk (kc,ln):  ln=(lh*32+lq) -> K[kv0+lq][kc*16+lh*8 .. +8]
//   V chunk (dt,kvs,ln):            -> V^T[dt*32+lq][kv0+kvs*16+lh*8 .. +8]
// ---------------------------------------------------------------------------
__global__ __launch_bounds__(256)
void fa_convert(const float* __restrict__ K, const float* __restrict__ V,
                char* __restrict__ ws) {
  __shared__ short tlds[BN * 130];  // 16640 B, V path only
  const int bid = blockIdx.x;
  const int tid = threadIdx.x;
  if (bid < 512) {  // K: bid = b*32 + kt
    const int b = bid >> 5, kt = bid & 31;
    const float* kb = K + (size_t)(b * S_LEN + kt * BN) * DK;
    short* out = (short*)(ws + (size_t)bid * TILE_B);
#pragma unroll
    for (int it = 0; it < 4; ++it) {
      int o = it * 256 + tid;
      int r = o >> 4, cix = o & 15;          // row in [0,64), 32B col-chunk
      const float* src = kb + r * DK + cix * 8;
      float4 x = *(const float4*)src;
      float4 y = *(const float4*)(src + 4);
      s16x8 f;
      f[0] = f2bf(x.x); f[1] = f2bf(x.y); f[2] = f2bf(x.z); f[3] = f2bf(x.w);
      f[4] = f2bf(y.x); f[5] = f2bf(y.y); f[6] = f2bf(y.z); f[7] = f2bf(y.w);
      int s2 = r >> 5, lq = r & 31, kc = cix >> 1, lh = cix & 1;
      int elem = s2 * 4096 + kc * 512 + (lh * 32 + lq) * 8;
      *(s16x8*)(out + elem) = f;
    }
  } else {  // V transpose via LDS: vb = b*32 + kt
    const int vb = bid - 512;
    const float* vbase = V + (size_t)((vb >> 5) * S_LEN + (vb & 31) * BN) * DV;
    short* out = (short*)(ws + VWS_OFF + (size_t)vb * TILE_B);
#pragma unroll
    for (int i = 0; i < 8; ++i) {
      int idx = i * 256 + tid;        // float4 index, 2048 total
      int r = idx >> 5, c4 = idx & 31;
      float4 x = *(const float4*)(vbase + r * DV + c4 * 4);
      unsigned lo = ((unsigned)(unsigned short)f2bf(x.y) << 16) |
                    (unsigned short)f2bf(x.x);
      unsigned hi = ((unsigned)(unsigned short)f2bf(x.w) << 16) |
                    (unsigned short)f2bf(x.z);
      *(unsigned*)&tlds[r * 130 + c4 * 4] = lo;
      *(unsigned*)&tlds[r * 130 + c4 * 4 + 2] = hi;
    }
    __syncthreads();
#pragma unroll
    for (int i = 0; i < 2; ++i) {
      int idx = i * 256 + tid;        // pair index, 512 total
      int dp = idx >> 3, cix = idx & 7;
      int d = dp * 2;                 // even d; d and d+1 share d>>5
      s16x8 f0, f1;
#pragma unroll
      for (int j = 0; j < 8; ++j) {
        int r = cix * 8 + j;
        unsigned two = *(const unsigned*)&tlds[r * 130 + d];
        f0[j] = (short)(two & 0xFFFFu);
        f1[j] = (short)(two >> 16);
      }
      int s2 = cix >> 2, c2 = cix & 3, kvs = c2 >> 1, lh = c2 & 1;
      int dt = d >> 5, lq = d & 31;
      int ebase = s2 * 4096 + (dt * 2 + kvs) * 512 + lh * 256;
      *(s16x8*)(out + ebase + lq * 8)       = f0;
      *(s16x8*)(out + ebase + (lq + 1) * 8) = f1;
    }
  }
}

// ---------------------------------------------------------------------------
// Pass 2 (wave-autonomous, 32x32 MFMA): 512 blocks x 4 waves; wave =
// (batch b, q 32-row tile qt, kv half h). NO barriers, NO LDS, P in registers
// (swapped QK^T + cvt_pk_bf16 + v_permlane32_swap). Fixed-m softmax (m=16):
// halves combine by plain addition (fa_combine).
// K double-buffered (kfA/kfB), loadK(s+1) issued BEFORE QK(s) -> K's
// issue-to-consume gap = one full step (~3000 cyc), covering loaded-L2
// latency. R8's runtime-parity loop (if(pa) step(kfA) else step(kfB)) made
// the allocator merge both paths and spill ~180MB scratch (VGPR pinned 128,
// WRITE 168MB); this version uses R3's EXPLICITLY UNROLLED even/odd loop --
// every kfA/kfB reference is compile-time static (rule-#20 discipline).
// V stays single-buffered (full dbuf would cross the 2-waves/SIMD cliff).
// Layouts (32x32x16 bf16): A/B: i=l&31, k=(l>>5)*8+e.
// C/D: col=l&31, row=(r&3)+8*(r>>2)+4*(l>>5)   [m74/m101 verified].
// Mapping: x=bid&7 (XCD), b=x+8*(j&1); blocks bid,bid+256 share a CU with
// complementary qg (sum=15) -> balanced ~130 steps/CU; heavy-first dispatch.
// ---------------------------------------------------------------------------
__global__ __launch_bounds__(256, 2)
void fa_main_wave(const float* __restrict__ Q, char* __restrict__ ws,
                  float* __restrict__ Out) {
  const int bid = blockIdx.x;           // [0,512)
  const int x = bid & 7, j = bid >> 3;  // j in [0,64)
  const int b = x + 8 * (j & 1);
  const int w = j >> 1;                 // [0,32)
  const int qg = (w < 16) ? (15 - (w >> 1)) : ((w - 16) >> 1);
  const int h  = w & 1;

  const int tid = threadIdx.x;
  const int wv = tid >> 6, ln = tid & 63;
  const int lq = ln & 31, lh = ln >> 5;
  const int qt = qg * 4 + wv;           // q 32-tile in [0,64)
  const int q0w = qt * 32;
  const int lb16 = ln * 16;             // coalesced per-lane byte offset
  const float scale2 = 0.12751741f;     // log2(e)/sqrt(128), folded into Q

  const int nkv = qt + 1;               // causal 32-kv subtiles for this q tile
  const int lo  = h ? ((nkv + 1) >> 1) : 0;
  const int hi2 = h ? nkv : ((nkv + 1) >> 1);

  // Q frags (B-operand): lane holds Q[q0w+lq][kc*16 + lh*8 + e] * scale2
  bf16x8 qf[8];
  {
    const float* qrow = Q + (size_t)(b * S_LEN + q0w + lq) * DK + lh * 8;
#pragma unroll
    for (int kc = 0; kc < 8; ++kc) {
      float4 xv = *(const float4*)(qrow + kc * 16);
      float4 yv = *(const float4*)(qrow + kc * 16 + 4);
      s16x8 f;
      f[0] = f2bf(xv.x * scale2); f[1] = f2bf(xv.y * scale2);
      f[2] = f2bf(xv.z * scale2); f[3] = f2bf(xv.w * scale2);
      f[4] = f2bf(yv.x * scale2); f[5] = f2bf(yv.y * scale2);
      f[6] = f2bf(yv.z * scale2); f[7] = f2bf(yv.w * scale2);
      qf[kc] = __builtin_bit_cast(bf16x8, f);
    }
  }

  const char* kbase = ws + (size_t)(b * NT) * TILE_B;
  const char* vbase = ws + VWS_OFF + (size_t)(b * NT) * TILE_B;

  f32x16 oacc[4];
#pragma unroll
  for (int dt = 0; dt < 4; ++dt)
#pragma unroll
    for (int r = 0; r < 16; ++r) oacc[dt][r] = 0.f;
  float lsum = 0.f;

  bf16x8 kfA[8], kfB[8], vf[4][2];

  auto loadK = [&](bf16x8 (&dst)[8], int s_) {
    const char* kp = kbase + (size_t)s_ * 8192;
#pragma unroll
    for (int kc = 0; kc < 8; ++kc) dst[kc] = gload8v(kp + kc * 1024 + lb16);
  };
  auto loadV = [&](int s_) {
    const char* vp = vbase + (size_t)s_ * 8192;
#pragma unroll
    for (int dt = 0; dt < 4; ++dt)
#pragma unroll
      for (int kvs = 0; kvs < 2; ++kvs)
        vf[dt][kvs] = gload8v(vp + (dt * 2 + kvs) * 1024 + lb16);
  };
  // full step body on K-fragment set kfr, subtile s
  auto step = [&](bf16x8 (&kfr)[8], int s) {
    // S^T = K Q^T : lane holds S^T[kv=crow(r,lh)][q=lq] (pre-scaled, base-2)
    f32x16 st;
#pragma unroll
    for (int r = 0; r < 16; ++r) st[r] = 0.f;
    __builtin_amdgcn_s_setprio(1);
#pragma unroll
    for (int kc = 0; kc < 8; ++kc)
      st = __builtin_amdgcn_mfma_f32_32x32x16_bf16(kfr[kc], qf[kc], st, 0, 0, 0);
    __builtin_amdgcn_s_setprio(0);
    if (s == qt) {  // causal mask, diagonal tile only
#pragma unroll
      for (int r = 0; r < 16; ++r)
        if (((r & 3) + 8 * (r >> 2) + 4 * lh) > lq) st[r] = -1e30f;
    }
    // fixed-m softmax: P = 2^(st-16); m cancels in O = acc/l exactly
    float p[16];
#pragma unroll
    for (int r = 0; r < 16; ++r) {
      p[r] = __builtin_amdgcn_exp2f(st[r] - 16.0f);
      lsum += p[r];
    }
    // pack P^T into PV B-operand frags: kv = kvs*16 + lh*8 + e at q=lq
    unsigned a0 = cvtpk(p[0], p[1]), b0 = cvtpk(p[4], p[5]);
    unsigned a1 = cvtpk(p[2], p[3]), b1 = cvtpk(p[6], p[7]);
    plswap(a0, b0); plswap(a1, b1);
    u32x4 w0; w0[0] = a0; w0[1] = a1; w0[2] = b0; w0[3] = b1;
    bf16x8 pa0 = __builtin_bit_cast(bf16x8, w0);
    unsigned a2 = cvtpk(p[8], p[9]),   b2 = cvtpk(p[12], p[13]);
    unsigned a3 = cvtpk(p[10], p[11]), b3 = cvtpk(p[14], p[15]);
    plswap(a2, b2); plswap(a3, b3);
    u32x4 w1; w1[0] = a2; w1[1] = a3; w1[2] = b2; w1[3] = b3;
    bf16x8 pa1 = __builtin_bit_cast(bf16x8, w1);
    // O^T += V^T P^T : lane holds O^T[d=dt*32+crow(r,lh)][q=lq]
    __builtin_amdgcn_s_setprio(1);
#pragma unroll
    for (int dt = 0; dt < 4; ++dt)
      oacc[dt] = __builtin_amdgcn_mfma_f32_32x32x16_bf16(vf[dt][0], pa0, oacc[dt], 0, 0, 0);
#pragma unroll
    for (int dt = 0; dt < 4; ++dt)
      oacc[dt] = __builtin_amdgcn_mfma_f32_32x32x16_bf16(vf[dt][1], pa1, oacc[dt], 0, 0, 0);
    __builtin_amdgcn_s_setprio(0);
  };

  if (lo < hi2) {
    loadK(kfA, lo);
    loadV(lo);
    int s = lo;
    // explicitly unrolled even/odd pipeline: all buffer refs static
    while (s + 1 < hi2) {
      // step s out of kfA; K(s+1) -> kfB issued BEFORE QK(s)
      loadK(kfB, s + 1);
      step(kfA, s);
      loadV(s + 1);                  // after PV(s) consumed vf
      ++s;
      if (s + 1 < hi2) {
        loadK(kfA, s + 1);           // before QK(s) on kfB
        step(kfB, s);
        loadV(s + 1);
        ++s;
      } else {
        step(kfB, s);
        ++s;
        break;                       // s == hi2
      }
    }
    if (s < hi2) step(kfA, s);       // odd-count tail
  }

  // epilogue: store UNNORMALIZED partial acc + l; combine kernel finishes.
  lsum += __shfl_xor(lsum, 32);  // lanes l and l+32 hold same q
  float* obase = h ? (float*)(ws + PART_OFF) : Out;
  float* lb = (float*)(ws + (h ? L1_OFF : L0_OFF)) + (size_t)b * S_LEN;
  if (lh == 0) lb[q0w + lq] = lsum;
  float* ob = obase + (size_t)(b * S_LEN + q0w + lq) * DV;
#pragma unroll
  for (int dt = 0; dt < 4; ++dt)
#pragma unroll
    for (int g = 0; g < 4; ++g) {
      f32x4 v = {oacc[dt][g * 4 + 0], oacc[dt][g * 4 + 1],
                 oacc[dt][g * 4 + 2], oacc[dt][g * 4 + 3]};
      *(f32x4*)(ob + dt * 32 + g * 8 + 4 * lh) = v;
    }
}

// Combine: Out = (Out + P1) / (l0 + l1). 2048 blocks x 256 threads x 8 floats.
// XCD-remapped: bid&7 = XCD, b = (bid&7)+8*((bid>>3)&1) matches fa_main_wave's
// batch->XCD mapping, so each XCD combines its own partials (L2-resident).
__global__ __launch_bounds__(256)
void fa_combine(float* __restrict__ Out, const char* __restrict__ ws) {
  const float* P1 = (const float*)(ws + PART_OFF);
  const float* L0 = (const float*)(ws + L0_OFF);
  const float* L1 = (const float*)(ws + L1_OFF);
  const int bid = blockIdx.x;
  const int b = (bid & 7) + 8 * ((bid >> 3) & 1);
  const int chunk = bid >> 4;  // [0,128) chunks of 2048 floats per batch
  const int base = b * (S_LEN * DV) + chunk * 2048 + threadIdx.x * 8;
  const int q = base >> 7;  // global row in [0, 16*2048)
  float inv = 1.0f / (L0[q] + L1[q]);
  f32x4 a0 = *(const f32x4*)(Out + base);
  f32x4 a1 = *(const f32x4*)(P1 + base);
  f32x4 b0 = *(const f32x4*)(Out + base + 4);
  f32x4 b1 = *(const f32x4*)(P1 + base + 4);
  *(f32x4*)(Out + base)     = (a0 + a1) * inv;
  *(f32x4*)(Out + base + 4) = (b0 + b1) * inv;
}

// ---------------------------------------------------------------------------
// Fallback (ws too small for split buffers): verified single-pass kernel,
// in-kernel convert, self-contained (no ws layout dependence).
// ---------------------------------------------------------------------------
#define LDP 72
__global__ __launch_bounds__(256)
void fa_fallback(const float* __restrict__ Q, const float* __restrict__ K,
                 const float* __restrict__ V, float* __restrict__ Out) {
  __shared__ __align__(16) short lds_k[BN * 136];
  __shared__ __align__(16) short lds_vt[DV * 72];
  __shared__ __align__(16) short lds_p[4 * 16 * LDP];

  const int bid = blockIdx.x;
  const int b = bid >> 5, t = bid & 31;
  const int q0 = t * 64;
  const int tid = threadIdx.x;
  const int wv = tid >> 6, ln = tid & 63;
  const int c = ln & 15, qd = ln >> 4;
  const float scale2 = 0.12751741f;
  const int qg = q0 + wv * 16 + c;

  bf16x8 qf[4];
  {
    const float* qrow = Q + (size_t)(b * S_LEN + qg) * DK + qd * 8;
#pragma unroll
    for (int t4 = 0; t4 < 4; ++t4) {
      float4 x = *(const float4*)(qrow + t4 * 32);
      float4 y = *(const float4*)(qrow + t4 * 32 + 4);
      s16x8 f;
      f[0] = f2bf(x.x * scale2); f[1] = f2bf(x.y * scale2);
      f[2] = f2bf(x.z * scale2); f[3] = f2bf(x.w * scale2);
      f[4] = f2bf(y.x * scale2); f[5] = f2bf(y.y * scale2);
      f[6] = f2bf(y.z * scale2); f[7] = f2bf(y.w * scale2);
      qf[t4] = __builtin_bit_cast(bf16x8, f);
    }
  }
  f32x4 oacc[8];
#pragma unroll
  for (int i = 0; i < 8; ++i) oacc[i] = f32x4{0.f, 0.f, 0.f, 0.f};
  float m_i = -1e30f, l_i = 0.f;
  const float* kbb = K + (size_t)b * S_LEN * DK;
  const float* vbb = V + (size_t)b * S_LEN * DV;
  short* pb = &lds_p[wv * 16 * LDP];

  for (int kt = 0; kt <= t; ++kt) {
    const int kv0 = kt * BN;
    __syncthreads();
    {
      const float* kb = kbb + (size_t)kv0 * DK;
#pragma unroll
      for (int it = 0; it < 8; ++it) {
        int flat = it * 256 + tid;
        int r = flat >> 5, d4 = flat & 31;
        float4 x = *(const float4*)(kb + r * DK + d4 * 4);
        s16x4 s;
        s[0] = f2bf(x.x); s[1] = f2bf(x.y); s[2] = f2bf(x.z); s[3] = f2bf(x.w);
        *(s16x4*)&lds_k[r * 136 + d4 * 4] = s;
      }
      const float* vb = vbb + (size_t)kv0 * DV;
#pragma unroll
      for (int it = 0; it < 8; ++it) {
        int flat = it * 256 + tid;
        int d = flat & 127, r0 = (flat >> 7) << 2;
        s16x4 s;
        s[0] = f2bf(vb[(r0 + 0) * DV + d]);
        s[1] = f2bf(vb[(r0 + 1) * DV + d]);
        s[2] = f2bf(vb[(r0 + 2) * DV + d]);
        s[3] = f2bf(vb[(r0 + 3) * DV + d]);
        *(s16x4*)&lds_vt[d * 72 + r0] = s;
      }
    }
    __syncthreads();
    f32x4 st[4];
#pragma unroll
    for (int cb = 0; cb < 4; ++cb) {
      f32x4 acc = f32x4{0.f, 0.f, 0.f, 0.f};
      const short* kr = &lds_k[(cb * 16 + c) * 136 + qd * 8];
#pragma unroll
      for (int t4 = 0; t4 < 4; ++t4)
        acc = __builtin_amdgcn_mfma_f32_16x16x32_bf16(lds8(kr + t4 * 32), qf[t4], acc, 0, 0, 0);
      st[cb] = acc;
    }
    if (kt == t) {
#pragma unroll
      for (int cb = 0; cb < 4; ++cb)
#pragma unroll
        for (int r = 0; r < 4; ++r)
          if (cb * 16 + qd * 4 + r > wv * 16 + c) st[cb][r] = -1e30f;
    }
    float tmax = -1e30f;
#pragma unroll
    for (int cb = 0; cb < 4; ++cb)
#pragma unroll
      for (int r = 0; r < 4; ++r) tmax = fmaxf(tmax, st[cb][r]);
    tmax = fmaxf(tmax, __shfl_xor(tmax, 16));
    tmax = fmaxf(tmax, __shfl_xor(tmax, 32));
    float mn = fmaxf(m_i, tmax);
    float al = __builtin_amdgcn_exp2f(m_i - mn);
    m_i = mn;
    float tsum = 0.f;
#pragma unroll
    for (int cb = 0; cb < 4; ++cb) {
      s16x4 pk;
#pragma unroll
      for (int r = 0; r < 4; ++r) {
        float p = __builtin_amdgcn_exp2f(st[cb][r] - m_i);
        tsum += p;
        pk[r] = f2bf(p);
      }
      *(s16x4*)&pb[c * LDP + cb * 16 + qd * 4] = pk;
    }
    tsum += __shfl_xor(tsum, 16);
    tsum += __shfl_xor(tsum, 32);
    l_i = l_i * al + tsum;
#pragma unroll
    for (int i = 0; i < 8; ++i)
#pragma unroll
      for (int r = 0; r < 4; ++r) oacc[i][r] *= al;
#pragma unroll
    for (int t2 = 0; t2 < 2; ++t2) {
      bf16x8 pf = lds8(&pb[c * LDP + t2 * 32 + qd * 8]);
#pragma unroll
      for (int cb2 = 0; cb2 < 8; ++cb2) {
        bf16x8 vf = lds8(&lds_vt[(cb2 * 16 + c) * 72 + t2 * 32 + qd * 8]);
        oacc[cb2] = __builtin_amdgcn_mfma_f32_16x16x32_bf16(vf, pf, oacc[cb2], 0, 0, 0);
      }
    }
  }
  float inv = 1.0f / l_i;
  float* ob = Out + (size_t)(b * S_LEN + qg) * DV;
#pragma unroll
  for (int cb2 = 0; cb2 < 8; ++cb2) {
    f32x4 v = oacc[cb2] * inv;
    *(f32x4*)(ob + cb2 * 16 + qd * 4) = v;
  }
}

extern "C" void kernel_launch(void* const* d_in, const int* in_sizes, int n_in,
                              void* d_out, int out_size, void* d_ws, size_t ws_size,
                              hipStream_t stream) {
  (void)in_sizes; (void)n_in; (void)out_size;
  const float* Q = (const float*)d_in[0];
  const float* K = (const float*)d_in[1];
  const float* V = (const float*)d_in[2];
  float* O = (float*)d_out;
  if (ws_size >= WS_NEED_SPLIT) {
    fa_convert<<<dim3(1024), dim3(256), 0, stream>>>(K, V, (char*)d_ws);
    fa_main_wave<<<dim3(512), dim3(256), 0, stream>>>(Q, (char*)d_ws, O);
    fa_combine<<<dim3(2048), dim3(256), 0, stream>>>(O, (const char*)d_ws);
  } else {
    fa_fallback<<<dim3(512), dim3(256), 0, stream>>>(Q, K, V, O);
  }
}

// Round 10
// 227.965 us; speedup vs baseline: 1.7497x; 1.7497x over previous
//
#include <hip/hip_runtime.h>
#include <hip/hip_bf16.h>

#define S_LEN 2048
#define DK 128
#define DV 128
#define BN 64     // KV rows per ws tile (2 subtiles of 32)
#define NT 32     // KV 64-tiles per batch
#define TILE_B 16384                        // bytes per 64x128 bf16 tile
#define VWS_OFF ((size_t)16 * NT * TILE_B)  // 8.39 MB
#define WS_NEED ((size_t)2 * 16 * NT * TILE_B)
// split-KV partial buffers
#define PART_OFF WS_NEED                              // h=1 acc partial, 16.78 MB
#define PART_B   ((size_t)16 * S_LEN * DV * 4)
#define L0_OFF   (PART_OFF + PART_B)                  // l partials, 128 KB each
#define L1_OFF   (L0_OFF + (size_t)16 * S_LEN * 4)
#define WS_NEED_SPLIT (L1_OFF + (size_t)16 * S_LEN * 4)

typedef __attribute__((ext_vector_type(8))) short s16x8;
typedef __attribute__((ext_vector_type(4))) short s16x4;
typedef __attribute__((ext_vector_type(8))) __bf16 bf16x8;
typedef __attribute__((ext_vector_type(4))) float f32x4;
typedef __attribute__((ext_vector_type(16))) float f32x16;
typedef __attribute__((ext_vector_type(4))) unsigned u32x4;

__device__ __forceinline__ short f2bf(float f) {
  unsigned u = __builtin_bit_cast(unsigned, f);
  u += 0x7FFFu + ((u >> 16) & 1u);
  return (short)(u >> 16);
}
__device__ __forceinline__ bf16x8 lds8(const short* p) {
  return __builtin_bit_cast(bf16x8, *(const s16x8*)p);
}
__device__ __forceinline__ bf16x8 gload8v(const char* p) {
  return __builtin_bit_cast(bf16x8, *(const s16x8*)p);
}
// async global->LDS, 16B/lane; LDS dest = wave-uniform base + lane*16
__device__ __forceinline__ void gload16(const void* g, void* l) {
  __builtin_amdgcn_global_load_lds(
      (const __attribute__((address_space(1))) void*)g,
      (__attribute__((address_space(3))) void*)l, 16, 0, 0);
}
// packed f32x2 -> bf16x2 (RNE): low = a, high = b
__device__ __forceinline__ unsigned cvtpk(float a, float b) {
  unsigned r;
  asm("v_cvt_pk_bf16_f32 %0, %1, %2" : "=v"(r) : "v"(a), "v"(b));
  return r;
}
// v_permlane32_swap_b32: a'[l] = l<32 ? a[l] : b[l-32];
//                        b'[l] = l<32 ? a[l+32] : b[l]
__device__ __forceinline__ void plswap(unsigned& a, unsigned& b) {
  asm volatile("s_nop 1\n\tv_permlane32_swap_b32 %0, %1" : "+v"(a), "+v"(b));
}

// ---------------------------------------------------------------------------
// Pass 1: convert K -> bf16, V -> bf16-transposed, FRAGMENT-MAJOR (R7):
// per 32-kv subtile (8192 B), lane ln's 16B chunk for fragment f lives at
// subtile*8192 + f*1024 + ln*16 -> every main-kernel frag access is one
// contiguous 128B-aligned 1KB block (8 cache lines, minimum), and is ALSO
// exactly the linear pattern global_load_lds requires.
//   K chunk (kc,ln):  ln=(lh*32+lq) -> K[kv0+lq][kc*16+lh*8 .. +8]
//   V chunk (dt,kvs,ln):            -> V^T[dt*32+lq][kv0+kvs*16+lh*8 .. +8]
// ---------------------------------------------------------------------------
__global__ __launch_bounds__(256)
void fa_convert(const float* __restrict__ K, const float* __restrict__ V,
                char* __restrict__ ws) {
  __shared__ short tlds[BN * 130];  // 16640 B, V path only
  const int bid = blockIdx.x;
  const int tid = threadIdx.x;
  if (bid < 512) {  // K: bid = b*32 + kt
    const int b = bid >> 5, kt = bid & 31;
    const float* kb = K + (size_t)(b * S_LEN + kt * BN) * DK;
    short* out = (short*)(ws + (size_t)bid * TILE_B);
#pragma unroll
    for (int it = 0; it < 4; ++it) {
      int o = it * 256 + tid;
      int r = o >> 4, cix = o & 15;          // row in [0,64), 32B col-chunk
      const float* src = kb + r * DK + cix * 8;
      float4 x = *(const float4*)src;
      float4 y = *(const float4*)(src + 4);
      s16x8 f;
      f[0] = f2bf(x.x); f[1] = f2bf(x.y); f[2] = f2bf(x.z); f[3] = f2bf(x.w);
      f[4] = f2bf(y.x); f[5] = f2bf(y.y); f[6] = f2bf(y.z); f[7] = f2bf(y.w);
      int s2 = r >> 5, lq = r & 31, kc = cix >> 1, lh = cix & 1;
      int elem = s2 * 4096 + kc * 512 + (lh * 32 + lq) * 8;
      *(s16x8*)(out + elem) = f;
    }
  } else {  // V transpose via LDS: vb = b*32 + kt
    const int vb = bid - 512;
    const float* vbase = V + (size_t)((vb >> 5) * S_LEN + (vb & 31) * BN) * DV;
    short* out = (short*)(ws + VWS_OFF + (size_t)vb * TILE_B);
#pragma unroll
    for (int i = 0; i < 8; ++i) {
      int idx = i * 256 + tid;        // float4 index, 2048 total
      int r = idx >> 5, c4 = idx & 31;
      float4 x = *(const float4*)(vbase + r * DV + c4 * 4);
      unsigned lo = ((unsigned)(unsigned short)f2bf(x.y) << 16) |
                    (unsigned short)f2bf(x.x);
      unsigned hi = ((unsigned)(unsigned short)f2bf(x.w) << 16) |
                    (unsigned short)f2bf(x.z);
      *(unsigned*)&tlds[r * 130 + c4 * 4] = lo;
      *(unsigned*)&tlds[r * 130 + c4 * 4 + 2] = hi;
    }
    __syncthreads();
#pragma unroll
    for (int i = 0; i < 2; ++i) {
      int idx = i * 256 + tid;        // pair index, 512 total
      int dp = idx >> 3, cix = idx & 7;
      int d = dp * 2;                 // even d; d and d+1 share d>>5
      s16x8 f0, f1;
#pragma unroll
      for (int j = 0; j < 8; ++j) {
        int r = cix * 8 + j;
        unsigned two = *(const unsigned*)&tlds[r * 130 + d];
        f0[j] = (short)(two & 0xFFFFu);
        f1[j] = (short)(two >> 16);
      }
      int s2 = cix >> 2, c2 = cix & 3, kvs = c2 >> 1, lh = c2 & 1;
      int dt = d >> 5, lq = d & 31;
      int ebase = s2 * 4096 + (dt * 2 + kvs) * 512 + lh * 256;
      *(s16x8*)(out + ebase + lq * 8)       = f0;
      *(s16x8*)(out + ebase + (lq + 1) * 8) = f1;
    }
  }
}

// ---------------------------------------------------------------------------
// Pass 2 (wave-autonomous, 32x32 MFMA): 512 blocks x 4 waves; wave =
// (batch b, q 32-row tile qt, kv half h). No barriers, no cross-wave LDS,
// P in registers (swapped QK^T + cvt_pk_bf16 + v_permlane32_swap).
// Fixed-m softmax (m=16): halves combine by plain addition (fa_combine).
// R10: K prefetch via global_load_lds into per-wave PRIVATE LDS double
// buffers (2 x 8KB/wave, 64KB/block, 128KB/CU at 2 blocks). Register
// double-buffering is unaffordable: at 2 waves/SIMD the combined
// VGPR+AGPR cap is 256/wave; R7's inventory is ~244, +32 for kfB spilled
// ~0.5GB/dispatch in R8/R9 (VGPR pinned 128). global_load_lds costs ZERO
// registers: glds K(s+1) issued at TOP of step s (full-step gap covers L2
// latency), vmcnt(16) steady-state / vmcnt(8) at finals, then ds_read_b128.
// Same-wave issue order + compiler lgkmcnt drains make the LDS WAR safe
// without barriers. V stays reg-single-buffered (R7 pattern).
// Layouts (32x32x16 bf16): A/B: i=l&31, k=(l>>5)*8+e.
// C/D: col=l&31, row=(r&3)+8*(r>>2)+4*(l>>5)   [m74/m101 verified].
// Mapping: x=bid&7 (XCD), b=x+8*(j&1); blocks bid,bid+256 share a CU with
// complementary qg (sum=15) -> balanced ~130 steps/CU; heavy-first dispatch.
// ---------------------------------------------------------------------------
__global__ __launch_bounds__(256, 2)
void fa_main_wave(const float* __restrict__ Q, char* __restrict__ ws,
                  float* __restrict__ Out) {
  __shared__ __align__(16) char lds_kb[2][4][8192];  // [parity][wave][tile]

  const int bid = blockIdx.x;           // [0,512)
  const int x = bid & 7, j = bid >> 3;  // j in [0,64)
  const int b = x + 8 * (j & 1);
  const int w = j >> 1;                 // [0,32)
  const int qg = (w < 16) ? (15 - (w >> 1)) : ((w - 16) >> 1);
  const int h  = w & 1;

  const int tid = threadIdx.x;
  const int wv = tid >> 6, ln = tid & 63;
  const int lq = ln & 31, lh = ln >> 5;
  const int qt = qg * 4 + wv;           // q 32-tile in [0,64)
  const int q0w = qt * 32;
  const int lb16 = ln * 16;             // coalesced per-lane byte offset
  const float scale2 = 0.12751741f;     // log2(e)/sqrt(128), folded into Q

  const int nkv = qt + 1;               // causal 32-kv subtiles for this q tile
  const int lo  = h ? ((nkv + 1) >> 1) : 0;
  const int hi2 = h ? nkv : ((nkv + 1) >> 1);

  // Q frags (B-operand): lane holds Q[q0w+lq][kc*16 + lh*8 + e] * scale2
  bf16x8 qf[8];
  {
    const float* qrow = Q + (size_t)(b * S_LEN + q0w + lq) * DK + lh * 8;
#pragma unroll
    for (int kc = 0; kc < 8; ++kc) {
      float4 xv = *(const float4*)(qrow + kc * 16);
      float4 yv = *(const float4*)(qrow + kc * 16 + 4);
      s16x8 f;
      f[0] = f2bf(xv.x * scale2); f[1] = f2bf(xv.y * scale2);
      f[2] = f2bf(xv.z * scale2); f[3] = f2bf(xv.w * scale2);
      f[4] = f2bf(yv.x * scale2); f[5] = f2bf(yv.y * scale2);
      f[6] = f2bf(yv.z * scale2); f[7] = f2bf(yv.w * scale2);
      qf[kc] = __builtin_bit_cast(bf16x8, f);
    }
  }

  const char* kbase = ws + (size_t)(b * NT) * TILE_B;
  const char* vbase = ws + VWS_OFF + (size_t)(b * NT) * TILE_B;

  f32x16 oacc[4];
#pragma unroll
  for (int dt = 0; dt < 4; ++dt)
#pragma unroll
    for (int r = 0; r < 16; ++r) oacc[dt][r] = 0.f;
  float lsum = 0.f;

  bf16x8 kf[8], vf[4][2];

  // async-stage K subtile s_ into per-wave LDS buffer p (no registers used)
  auto gldsK = [&](int p, int s_) {
    const char* kp = kbase + (size_t)s_ * 8192 + lb16;
    char* lbase = &lds_kb[p][wv][0];
#pragma unroll
    for (int kc = 0; kc < 8; ++kc)
      gload16(kp + kc * 1024, lbase + kc * 1024);
  };
  auto readK = [&](int p) {
#pragma unroll
    for (int kc = 0; kc < 8; ++kc)
      kf[kc] = lds8((const short*)&lds_kb[p][wv][kc * 1024 + lb16]);
  };
  auto loadV = [&](int s_) {
    const char* vp = vbase + (size_t)s_ * 8192;
#pragma unroll
    for (int dt = 0; dt < 4; ++dt)
#pragma unroll
      for (int kvs = 0; kvs < 2; ++kvs)
        vf[dt][kvs] = gload8v(vp + (dt * 2 + kvs) * 1024 + lb16);
  };
  // full step body, subtile s (kf already read from LDS)
  auto step = [&](int s) {
    // S^T = K Q^T : lane holds S^T[kv=crow(r,lh)][q=lq] (pre-scaled, base-2)
    f32x16 st;
#pragma unroll
    for (int r = 0; r < 16; ++r) st[r] = 0.f;
    __builtin_amdgcn_s_setprio(1);
#pragma unroll
    for (int kc = 0; kc < 8; ++kc)
      st = __builtin_amdgcn_mfma_f32_32x32x16_bf16(kf[kc], qf[kc], st, 0, 0, 0);
    __builtin_amdgcn_s_setprio(0);
    if (s == qt) {  // causal mask, diagonal tile only
#pragma unroll
      for (int r = 0; r < 16; ++r)
        if (((r & 3) + 8 * (r >> 2) + 4 * lh) > lq) st[r] = -1e30f;
    }
    // fixed-m softmax: P = 2^(st-16); m cancels in O = acc/l exactly
    float p[16];
#pragma unroll
    for (int r = 0; r < 16; ++r) {
      p[r] = __builtin_amdgcn_exp2f(st[r] - 16.0f);
      lsum += p[r];
    }
    // pack P^T into PV B-operand frags: kv = kvs*16 + lh*8 + e at q=lq
    unsigned a0 = cvtpk(p[0], p[1]), b0 = cvtpk(p[4], p[5]);
    unsigned a1 = cvtpk(p[2], p[3]), b1 = cvtpk(p[6], p[7]);
    plswap(a0, b0); plswap(a1, b1);
    u32x4 w0; w0[0] = a0; w0[1] = a1; w0[2] = b0; w0[3] = b1;
    bf16x8 pa0 = __builtin_bit_cast(bf16x8, w0);
    unsigned a2 = cvtpk(p[8], p[9]),   b2 = cvtpk(p[12], p[13]);
    unsigned a3 = cvtpk(p[10], p[11]), b3 = cvtpk(p[14], p[15]);
    plswap(a2, b2); plswap(a3, b3);
    u32x4 w1; w1[0] = a2; w1[1] = a3; w1[2] = b2; w1[3] = b3;
    bf16x8 pa1 = __builtin_bit_cast(bf16x8, w1);
    // O^T += V^T P^T : lane holds O^T[d=dt*32+crow(r,lh)][q=lq]
    __builtin_amdgcn_s_setprio(1);
#pragma unroll
    for (int dt = 0; dt < 4; ++dt)
      oacc[dt] = __builtin_amdgcn_mfma_f32_32x32x16_bf16(vf[dt][0], pa0, oacc[dt], 0, 0, 0);
#pragma unroll
    for (int dt = 0; dt < 4; ++dt)
      oacc[dt] = __builtin_amdgcn_mfma_f32_32x32x16_bf16(vf[dt][1], pa1, oacc[dt], 0, 0, 0);
    __builtin_amdgcn_s_setprio(0);
  };

  if (lo < hi2) {
    gldsK(0, lo);                       // prologue stage into buf0
    loadV(lo);
    int s = lo;
    while (s + 1 < hi2) {
      // step s from buf0; K(s+1) -> buf1 issued BEFORE the wait+compute
      gldsK(1, s + 1);
      // wait K(s) group only: outstanding <= K(s)8 + V(s)8 + K(s+1)8
      asm volatile("s_waitcnt vmcnt(16)" ::: "memory");
      readK(0);
      step(s);
      loadV(s + 1);
      ++s;
      if (s + 1 < hi2) {
        gldsK(0, s + 1);
        asm volatile("s_waitcnt vmcnt(16)" ::: "memory");
        readK(1);
        step(s);
        loadV(s + 1);
        ++s;
      } else {
        // final step from buf1: outstanding = K(s)8 + V(s)8 -> vmcnt(8)
        asm volatile("s_waitcnt vmcnt(8)" ::: "memory");
        readK(1);
        step(s);
        ++s;
        break;
      }
    }
    if (s < hi2) {  // n==1 or even-count tail: final step from buf0
      asm volatile("s_waitcnt vmcnt(8)" ::: "memory");
      readK(0);
      step(s);
    }
  }

  // epilogue: store UNNORMALIZED partial acc + l; combine kernel finishes.
  lsum += __shfl_xor(lsum, 32);  // lanes l and l+32 hold same q
  float* obase = h ? (float*)(ws + PART_OFF) : Out;
  float* lb = (float*)(ws + (h ? L1_OFF : L0_OFF)) + (size_t)b * S_LEN;
  if (lh == 0) lb[q0w + lq] = lsum;
  float* ob = obase + (size_t)(b * S_LEN + q0w + lq) * DV;
#pragma unroll
  for (int dt = 0; dt < 4; ++dt)
#pragma unroll
    for (int g = 0; g < 4; ++g) {
      f32x4 v = {oacc[dt][g * 4 + 0], oacc[dt][g * 4 + 1],
                 oacc[dt][g * 4 + 2], oacc[dt][g * 4 + 3]};
      *(f32x4*)(ob + dt * 32 + g * 8 + 4 * lh) = v;
    }
}

// Combine: Out = (Out + P1) / (l0 + l1). 2048 blocks x 256 threads x 8 floats.
// XCD-remapped: bid&7 = XCD, b = (bid&7)+8*((bid>>3)&1) matches fa_main_wave's
// batch->XCD mapping, so each XCD combines its own partials (L2-resident).
__global__ __launch_bounds__(256)
void fa_combine(float* __restrict__ Out, const char* __restrict__ ws) {
  const float* P1 = (const float*)(ws + PART_OFF);
  const float* L0 = (const float*)(ws + L0_OFF);
  const float* L1 = (const float*)(ws + L1_OFF);
  const int bid = blockIdx.x;
  const int b = (bid & 7) + 8 * ((bid >> 3) & 1);
  const int chunk = bid >> 4;  // [0,128) chunks of 2048 floats per batch
  const int base = b * (S_LEN * DV) + chunk * 2048 + threadIdx.x * 8;
  const int q = base >> 7;  // global row in [0, 16*2048)
  float inv = 1.0f / (L0[q] + L1[q]);
  f32x4 a0 = *(const f32x4*)(Out + base);
  f32x4 a1 = *(const f32x4*)(P1 + base);
  f32x4 b0 = *(const f32x4*)(Out + base + 4);
  f32x4 b1 = *(const f32x4*)(P1 + base + 4);
  *(f32x4*)(Out + base)     = (a0 + a1) * inv;
  *(f32x4*)(Out + base + 4) = (b0 + b1) * inv;
}

// ---------------------------------------------------------------------------
// Fallback (ws too small for split buffers): verified single-pass kernel,
// in-kernel convert, self-contained (no ws layout dependence).
// ---------------------------------------------------------------------------
#define LDP 72
__global__ __launch_bounds__(256)
void fa_fallback(const float* __restrict__ Q, const float* __restrict__ K,
                 const float* __restrict__ V, float* __restrict__ Out) {
  __shared__ __align__(16) short lds_k[BN * 136];
  __shared__ __align__(16) short lds_vt[DV * 72];
  __shared__ __align__(16) short lds_p[4 * 16 * LDP];

  const int bid = blockIdx.x;
  const int b = bid >> 5, t = bid & 31;
  const int q0 = t * 64;
  const int tid = threadIdx.x;
  const int wv = tid >> 6, ln = tid & 63;
  const int c = ln & 15, qd = ln >> 4;
  const float scale2 = 0.12751741f;
  const int qg = q0 + wv * 16 + c;

  bf16x8 qf[4];
  {
    const float* qrow = Q + (size_t)(b * S_LEN + qg) * DK + qd * 8;
#pragma unroll
    for (int t4 = 0; t4 < 4; ++t4) {
      float4 x = *(const float4*)(qrow + t4 * 32);
      float4 y = *(const float4*)(qrow + t4 * 32 + 4);
      s16x8 f;
      f[0] = f2bf(x.x * scale2); f[1] = f2bf(x.y * scale2);
      f[2] = f2bf(x.z * scale2); f[3] = f2bf(x.w * scale2);
      f[4] = f2bf(y.x * scale2); f[5] = f2bf(y.y * scale2);
      f[6] = f2bf(y.z * scale2); f[7] = f2bf(y.w * scale2);
      qf[t4] = __builtin_bit_cast(bf16x8, f);
    }
  }
  f32x4 oacc[8];
#pragma unroll
  for (int i = 0; i < 8; ++i) oacc[i] = f32x4{0.f, 0.f, 0.f, 0.f};
  float m_i = -1e30f, l_i = 0.f;
  const float* kbb = K + (size_t)b * S_LEN * DK;
  const float* vbb = V + (size_t)b * S_LEN * DV;
  short* pb = &lds_p[wv * 16 * LDP];

  for (int kt = 0; kt <= t; ++kt) {
    const int kv0 = kt * BN;
    __syncthreads();
    {
      const float* kb = kbb + (size_t)kv0 * DK;
#pragma unroll
      for (int it = 0; it < 8; ++it) {
        int flat = it * 256 + tid;
        int r = flat >> 5, d4 = flat & 31;
        float4 x = *(const float4*)(kb + r * DK + d4 * 4);
        s16x4 s;
        s[0] = f2bf(x.x); s[1] = f2bf(x.y); s[2] = f2bf(x.z); s[3] = f2bf(x.w);
        *(s16x4*)&lds_k[r * 136 + d4 * 4] = s;
      }
      const float* vb = vbb + (size_t)kv0 * DV;
#pragma unroll
      for (int it = 0; it < 8; ++it) {
        int flat = it * 256 + tid;
        int d = flat & 127, r0 = (flat >> 7) << 2;
        s16x4 s;
        s[0] = f2bf(vb[(r0 + 0) * DV + d]);
        s[1] = f2bf(vb[(r0 + 1) * DV + d]);
        s[2] = f2bf(vb[(r0 + 2) * DV + d]);
        s[3] = f2bf(vb[(r0 + 3) * DV + d]);
        *(s16x4*)&lds_vt[d * 72 + r0] = s;
      }
    }
    __syncthreads();
    f32x4 st[4];
#pragma unroll
    for (int cb = 0; cb < 4; ++cb) {
      f32x4 acc = f32x4{0.f, 0.f, 0.f, 0.f};
      const short* kr = &lds_k[(cb * 16 + c) * 136 + qd * 8];
#pragma unroll
      for (int t4 = 0; t4 < 4; ++t4)
        acc = __builtin_amdgcn_mfma_f32_16x16x32_bf16(lds8(kr + t4 * 32), qf[t4], acc, 0, 0, 0);
      st[cb] = acc;
    }
    if (kt == t) {
#pragma unroll
      for (int cb = 0; cb < 4; ++cb)
#pragma unroll
        for (int r = 0; r < 4; ++r)
          if (cb * 16 + qd * 4 + r > wv * 16 + c) st[cb][r] = -1e30f;
    }
    float tmax = -1e30f;
#pragma unroll
    for (int cb = 0; cb < 4; ++cb)
#pragma unroll
      for (int r = 0; r < 4; ++r) tmax = fmaxf(tmax, st[cb][r]);
    tmax = fmaxf(tmax, __shfl_xor(tmax, 16));
    tmax = fmaxf(tmax, __shfl_xor(tmax, 32));
    float mn = fmaxf(m_i, tmax);
    float al = __builtin_amdgcn_exp2f(m_i - mn);
    m_i = mn;
    float tsum = 0.f;
#pragma unroll
    for (int cb = 0; cb < 4; ++cb) {
      s16x4 pk;
#pragma unroll
      for (int r = 0; r < 4; ++r) {
        float p = __builtin_amdgcn_exp2f(st[cb][r] - m_i);
        tsum += p;
        pk[r] = f2bf(p);
      }
      *(s16x4*)&pb[c * LDP + cb * 16 + qd * 4] = pk;
    }
    tsum += __shfl_xor(tsum, 16);
    tsum += __shfl_xor(tsum, 32);
    l_i = l_i * al + tsum;
#pragma unroll
    for (int i = 0; i < 8; ++i)
#pragma unroll
      for (int r = 0; r < 4; ++r) oacc[i][r] *= al;
#pragma unroll
    for (int t2 = 0; t2 < 2; ++t2) {
      bf16x8 pf = lds8(&pb[c * LDP + t2 * 32 + qd * 8]);
#pragma unroll
      for (int cb2 = 0; cb2 < 8; ++cb2) {
        bf16x8 vf = lds8(&lds_vt[(cb2 * 16 + c) * 72 + t2 * 32 + qd * 8]);
        oacc[cb2] = __builtin_amdgcn_mfma_f32_16x16x32_bf16(vf, pf, oacc[cb2], 0, 0, 0);
      }
    }
  }
  float inv = 1.0f / l_i;
  float* ob = Out + (size_t)(b * S_LEN + qg) * DV;
#pragma unroll
  for (int cb2 = 0; cb2 < 8; ++cb2) {
    f32x4 v = oacc[cb2] * inv;
    *(f32x4*)(ob + cb2 * 16 + qd * 4) = v;
  }
}

extern "C" void kernel_launch(void* const* d_in, const int* in_sizes, int n_in,
                              void* d_out, int out_size, void* d_ws, size_t ws_size,
                              hipStream_t stream) {
  (void)in_sizes; (void)n_in; (void)out_size;
  const float* Q = (const float*)d_in[0];
  const float* K = (const float*)d_in[1];
  const float* V = (const float*)d_in[2];
  float* O = (float*)d_out;
  if (ws_size >= WS_NEED_SPLIT) {
    fa_convert<<<dim3(1024), dim3(256), 0, stream>>>(K, V, (char*)d_ws);
    fa_main_wave<<<dim3(512), dim3(256), 0, stream>>>(Q, (char*)d_ws, O);
    fa_combine<<<dim3(2048), dim3(256), 0, stream>>>(O, (const char*)d_ws);
  } else {
    fa_fallback<<<dim3(512), dim3(256), 0, stream>>>(Q, K, V, O);
  }
}

// Round 11
// 133.338 us; speedup vs baseline: 2.9913x; 1.7097x over previous
//
#include <hip/hip_runtime.h>
#include <hip/hip_bf16.h>

#define S_LEN 2048
#define DK 128
#define DV 128
#define BN 64     // KV rows per ws tile (2 subtiles of 32)
#define NT 32     // KV 64-tiles per batch
#define TILE_B 16384                        // bytes per 64x128 bf16 tile
#define VWS_OFF ((size_t)16 * NT * TILE_B)  // 8.39 MB
#define WS_NEED ((size_t)2 * 16 * NT * TILE_B)
// split-KV partial buffers
#define PART_OFF WS_NEED                              // h=1 acc partial, 16.78 MB
#define PART_B   ((size_t)16 * S_LEN * DV * 4)
#define L0_OFF   (PART_OFF + PART_B)                  // l partials, 128 KB each
#define L1_OFF   (L0_OFF + (size_t)16 * S_LEN * 4)
#define WS_NEED_SPLIT (L1_OFF + (size_t)16 * S_LEN * 4)

typedef __attribute__((ext_vector_type(8))) short s16x8;
typedef __attribute__((ext_vector_type(4))) short s16x4;
typedef __attribute__((ext_vector_type(8))) __bf16 bf16x8;
typedef __attribute__((ext_vector_type(4))) float f32x4;
typedef __attribute__((ext_vector_type(16))) float f32x16;
typedef __attribute__((ext_vector_type(4))) unsigned u32x4;

__device__ __forceinline__ short f2bf(float f) {
  unsigned u = __builtin_bit_cast(unsigned, f);
  u += 0x7FFFu + ((u >> 16) & 1u);
  return (short)(u >> 16);
}
__device__ __forceinline__ bf16x8 lds8(const short* p) {
  return __builtin_bit_cast(bf16x8, *(const s16x8*)p);
}
__device__ __forceinline__ bf16x8 gload8v(const char* p) {
  return __builtin_bit_cast(bf16x8, *(const s16x8*)p);
}
// async global->LDS, 16B/lane; LDS dest = wave-uniform base + lane*16
__device__ __forceinline__ void gload16(const void* g, void* l) {
  __builtin_amdgcn_global_load_lds(
      (const __attribute__((address_space(1))) void*)g,
      (__attribute__((address_space(3))) void*)l, 16, 0, 0);
}
// packed f32x2 -> bf16x2 (RNE): low = a, high = b
__device__ __forceinline__ unsigned cvtpk(float a, float b) {
  unsigned r;
  asm("v_cvt_pk_bf16_f32 %0, %1, %2" : "=v"(r) : "v"(a), "v"(b));
  return r;
}
// v_permlane32_swap_b32: a'[l] = l<32 ? a[l] : b[l-32];
//                        b'[l] = l<32 ? a[l+32] : b[l]
__device__ __forceinline__ void plswap(unsigned& a, unsigned& b) {
  asm volatile("s_nop 1\n\tv_permlane32_swap_b32 %0, %1" : "+v"(a), "+v"(b));
}

// ---------------------------------------------------------------------------
// Pass 1: convert K -> bf16, V -> bf16-transposed, FRAGMENT-MAJOR (R7):
// per 32-kv subtile (8192 B), lane ln's 16B chunk for fragment f lives at
// subtile*8192 + f*1024 + ln*16 -> every main-kernel frag access is one
// contiguous 128B-aligned 1KB block (8 cache lines, minimum), and is ALSO
// exactly the linear pattern global_load_lds requires.
//   K chunk (kc,ln):  ln=(lh*32+lq) -> K[kv0+lq][kc*16+lh*8 .. +8]
//   V chunk (dt,kvs,ln):            -> V^T[dt*32+lq][kv0+kvs*16+lh*8 .. +8]
// ---------------------------------------------------------------------------
__global__ __launch_bounds__(256)
void fa_convert(const float* __restrict__ K, const float* __restrict__ V,
                char* __restrict__ ws) {
  __shared__ short tlds[BN * 130];  // 16640 B, V path only
  const int bid = blockIdx.x;
  const int tid = threadIdx.x;
  if (bid < 512) {  // K: bid = b*32 + kt
    const int b = bid >> 5, kt = bid & 31;
    const float* kb = K + (size_t)(b * S_LEN + kt * BN) * DK;
    short* out = (short*)(ws + (size_t)bid * TILE_B);
#pragma unroll
    for (int it = 0; it < 4; ++it) {
      int o = it * 256 + tid;
      int r = o >> 4, cix = o & 15;          // row in [0,64), 32B col-chunk
      const float* src = kb + r * DK + cix * 8;
      float4 x = *(const float4*)src;
      float4 y = *(const float4*)(src + 4);
      s16x8 f;
      f[0] = f2bf(x.x); f[1] = f2bf(x.y); f[2] = f2bf(x.z); f[3] = f2bf(x.w);
      f[4] = f2bf(y.x); f[5] = f2bf(y.y); f[6] = f2bf(y.z); f[7] = f2bf(y.w);
      int s2 = r >> 5, lq = r & 31, kc = cix >> 1, lh = cix & 1;
      int elem = s2 * 4096 + kc * 512 + (lh * 32 + lq) * 8;
      *(s16x8*)(out + elem) = f;
    }
  } else {  // V transpose via LDS: vb = b*32 + kt
    const int vb = bid - 512;
    const float* vbase = V + (size_t)((vb >> 5) * S_LEN + (vb & 31) * BN) * DV;
    short* out = (short*)(ws + VWS_OFF + (size_t)vb * TILE_B);
#pragma unroll
    for (int i = 0; i < 8; ++i) {
      int idx = i * 256 + tid;        // float4 index, 2048 total
      int r = idx >> 5, c4 = idx & 31;
      float4 x = *(const float4*)(vbase + r * DV + c4 * 4);
      unsigned lo = ((unsigned)(unsigned short)f2bf(x.y) << 16) |
                    (unsigned short)f2bf(x.x);
      unsigned hi = ((unsigned)(unsigned short)f2bf(x.w) << 16) |
                    (unsigned short)f2bf(x.z);
      *(unsigned*)&tlds[r * 130 + c4 * 4] = lo;
      *(unsigned*)&tlds[r * 130 + c4 * 4 + 2] = hi;
    }
    __syncthreads();
#pragma unroll
    for (int i = 0; i < 2; ++i) {
      int idx = i * 256 + tid;        // pair index, 512 total
      int dp = idx >> 3, cix = idx & 7;
      int d = dp * 2;                 // even d; d and d+1 share d>>5
      s16x8 f0, f1;
#pragma unroll
      for (int j = 0; j < 8; ++j) {
        int r = cix * 8 + j;
        unsigned two = *(const unsigned*)&tlds[r * 130 + d];
        f0[j] = (short)(two & 0xFFFFu);
        f1[j] = (short)(two >> 16);
      }
      int s2 = cix >> 2, c2 = cix & 3, kvs = c2 >> 1, lh = c2 & 1;
      int dt = d >> 5, lq = d & 31;
      int ebase = s2 * 4096 + (dt * 2 + kvs) * 512 + lh * 256;
      *(s16x8*)(out + ebase + lq * 8)       = f0;
      *(s16x8*)(out + ebase + (lq + 1) * 8) = f1;
    }
  }
}

// ---------------------------------------------------------------------------
// Pass 2 (wave-autonomous, 32x32 MFMA): 512 blocks x 4 waves; wave =
// (batch b, q 32-row tile qt, kv half h). No barriers, no cross-wave LDS
// coupling, P in registers (swapped QK^T + cvt_pk + permlane32_swap).
// Fixed-m softmax (m=16): halves combine by plain addition (fa_combine).
//
// R11 = R10's zero-register K pipeline in R7's spill-free ROLLED loop shape:
//  - R7 rolled single-body loop -> 116 VGPR no spill; R9/R10's 2x-unrolled
//    loops (2-4 inlined step copies) -> allocator pinned 128 + GB-scale
//    scratch. Single body restores the fit.
//  - K prefetch via global_load_lds into per-wave PRIVATE LDS dbuf (2x8KB/
//    wave, 64KB/block, 128KB/CU @2 blocks): costs ZERO registers, and the
//    counted-vmcnt asm fences ("memory") PIN the issue points - plain
//    gload prefetches were being sunk to their use by the scheduler under
//    register pressure, re-exposing full L2 latency (the 45-50us wall).
//  - steady-state vmcnt(16): waits only K(s)'s 8 DMA ops; V(s)+K(s+1) stay
//    in flight across the fence. Final iter vmcnt(8). Compiler adds its own
//    wait for vf before PV (counted, not a drain).
//  - V single-buffered in regs; its loads are pinned between PV(s) and the
//    next iter's fence -> issue-to-consume >= readK+QK+softmax.
// LDS WAR safety: buffer nb receives K(s+1) DMA; nb was last ds_read at
// iter s-1, and those reads completed (lgkmcnt) before iter s-1's MFMAs;
// per-wave in-order issue makes overwrite safe without barriers.
// Layouts (32x32x16 bf16): A/B: i=l&31, k=(l>>5)*8+e.
// C/D: col=l&31, row=(r&3)+8*(r>>2)+4*(l>>5)   [m74/m101 verified].
// Mapping: x=bid&7 (XCD), b=x+8*(j&1); blocks bid,bid+256 share a CU with
// complementary qg (sum=15) -> balanced ~130 steps/CU; heavy-first dispatch.
// ---------------------------------------------------------------------------
__global__ __launch_bounds__(256, 2)
void fa_main_wave(const float* __restrict__ Q, char* __restrict__ ws,
                  float* __restrict__ Out) {
  __shared__ __align__(16) char lds_kb[2][4][8192];  // [parity][wave][tile]

  const int bid = blockIdx.x;           // [0,512)
  const int x = bid & 7, j = bid >> 3;  // j in [0,64)
  const int b = x + 8 * (j & 1);
  const int w = j >> 1;                 // [0,32)
  const int qg = (w < 16) ? (15 - (w >> 1)) : ((w - 16) >> 1);
  const int h  = w & 1;

  const int tid = threadIdx.x;
  const int wv = tid >> 6, ln = tid & 63;
  const int lq = ln & 31, lh = ln >> 5;
  const int qt = qg * 4 + wv;           // q 32-tile in [0,64)
  const int q0w = qt * 32;
  const int lb16 = ln * 16;             // coalesced per-lane byte offset
  const float scale2 = 0.12751741f;     // log2(e)/sqrt(128), folded into Q

  const int nkv = qt + 1;               // causal 32-kv subtiles for this q tile
  const int lo  = h ? ((nkv + 1) >> 1) : 0;
  const int hi2 = h ? nkv : ((nkv + 1) >> 1);

  // Q frags (B-operand): lane holds Q[q0w+lq][kc*16 + lh*8 + e] * scale2
  bf16x8 qf[8];
  {
    const float* qrow = Q + (size_t)(b * S_LEN + q0w + lq) * DK + lh * 8;
#pragma unroll
    for (int kc = 0; kc < 8; ++kc) {
      float4 xv = *(const float4*)(qrow + kc * 16);
      float4 yv = *(const float4*)(qrow + kc * 16 + 4);
      s16x8 f;
      f[0] = f2bf(xv.x * scale2); f[1] = f2bf(xv.y * scale2);
      f[2] = f2bf(xv.z * scale2); f[3] = f2bf(xv.w * scale2);
      f[4] = f2bf(yv.x * scale2); f[5] = f2bf(yv.y * scale2);
      f[6] = f2bf(yv.z * scale2); f[7] = f2bf(yv.w * scale2);
      qf[kc] = __builtin_bit_cast(bf16x8, f);
    }
  }

  const char* kbase = ws + (size_t)(b * NT) * TILE_B;
  const char* vbase = ws + VWS_OFF + (size_t)(b * NT) * TILE_B;

  f32x16 oacc[4];
#pragma unroll
  for (int dt = 0; dt < 4; ++dt)
#pragma unroll
    for (int r = 0; r < 16; ++r) oacc[dt][r] = 0.f;
  float lsum = 0.f;

  bf16x8 kf[8], vf[4][2];

  auto loadV = [&](int s_) {
    const char* vp = vbase + (size_t)s_ * 8192;
#pragma unroll
    for (int dt = 0; dt < 4; ++dt)
#pragma unroll
      for (int kvs = 0; kvs < 2; ++kvs)
        vf[dt][kvs] = gload8v(vp + (dt * 2 + kvs) * 1024 + lb16);
  };

  if (lo < hi2) {
    char* lk0 = &lds_kb[0][wv][0];
    char* lk1 = &lds_kb[1][wv][0];
    {  // prologue: K(lo) -> buf0 (8 DMA), V(lo) -> vf (8 loads); outstanding 16
      const char* kp = kbase + (size_t)lo * 8192 + lb16;
#pragma unroll
      for (int kc = 0; kc < 8; ++kc) gload16(kp + kc * 1024, lk0 + kc * 1024);
      loadV(lo);
    }
    for (int s = lo; s < hi2; ++s) {
      const int cur = (s - lo) & 1;
      char* rb = cur ? lk1 : lk0;   // LDS pointer select: address arith only
      char* nb = cur ? lk0 : lk1;
      if (s + 1 < hi2) {
        // issue K(s+1) DMA -> outstanding: K(s)8 + V(s)8 + K(s+1)8 = 24
        const char* kp = kbase + (size_t)(s + 1) * 8192 + lb16;
#pragma unroll
        for (int kc = 0; kc < 8; ++kc) gload16(kp + kc * 1024, nb + kc * 1024);
        // wait oldest 8 = K(s); V(s)+K(s+1) stay in flight across the fence
        asm volatile("s_waitcnt vmcnt(16)" ::: "memory");
      } else {
        // last iter: outstanding K(s)8 + V(s)8 -> wait K(s)
        asm volatile("s_waitcnt vmcnt(8)" ::: "memory");
      }
      // K frags from LDS (compiler inserts lgkmcnt before MFMA use)
#pragma unroll
      for (int kc = 0; kc < 8; ++kc)
        kf[kc] = lds8((const short*)(rb + kc * 1024 + lb16));

      // S^T = K Q^T : lane holds S^T[kv=crow(r,lh)][q=lq] (pre-scaled, base-2)
      f32x16 st;
#pragma unroll
      for (int r = 0; r < 16; ++r) st[r] = 0.f;
      __builtin_amdgcn_s_setprio(1);
#pragma unroll
      for (int kc = 0; kc < 8; ++kc)
        st = __builtin_amdgcn_mfma_f32_32x32x16_bf16(kf[kc], qf[kc], st, 0, 0, 0);
      __builtin_amdgcn_s_setprio(0);
      if (s == qt) {  // causal mask, diagonal tile only
#pragma unroll
        for (int r = 0; r < 16; ++r)
          if (((r & 3) + 8 * (r >> 2) + 4 * lh) > lq) st[r] = -1e30f;
      }
      // fixed-m softmax: P = 2^(st-16); m cancels in O = acc/l exactly
      float p[16];
#pragma unroll
      for (int r = 0; r < 16; ++r) {
        p[r] = __builtin_amdgcn_exp2f(st[r] - 16.0f);
        lsum += p[r];
      }
      // pack P^T into PV B-operand frags: kv = kvs*16 + lh*8 + e at q=lq
      unsigned a0 = cvtpk(p[0], p[1]), b0 = cvtpk(p[4], p[5]);
      unsigned a1 = cvtpk(p[2], p[3]), b1 = cvtpk(p[6], p[7]);
      plswap(a0, b0); plswap(a1, b1);
      u32x4 w0; w0[0] = a0; w0[1] = a1; w0[2] = b0; w0[3] = b1;
      bf16x8 pa0 = __builtin_bit_cast(bf16x8, w0);
      unsigned a2 = cvtpk(p[8], p[9]),   b2 = cvtpk(p[12], p[13]);
      unsigned a3 = cvtpk(p[10], p[11]), b3 = cvtpk(p[14], p[15]);
      plswap(a2, b2); plswap(a3, b3);
      u32x4 w1; w1[0] = a2; w1[1] = a3; w1[2] = b2; w1[3] = b3;
      bf16x8 pa1 = __builtin_bit_cast(bf16x8, w1);
      // O^T += V^T P^T (compiler inserts counted vmcnt for vf here)
      __builtin_amdgcn_s_setprio(1);
#pragma unroll
      for (int dt = 0; dt < 4; ++dt)
        oacc[dt] = __builtin_amdgcn_mfma_f32_32x32x16_bf16(vf[dt][0], pa0, oacc[dt], 0, 0, 0);
#pragma unroll
      for (int dt = 0; dt < 4; ++dt)
        oacc[dt] = __builtin_amdgcn_mfma_f32_32x32x16_bf16(vf[dt][1], pa1, oacc[dt], 0, 0, 0);
      __builtin_amdgcn_s_setprio(0);
      // V(s+1): pinned between PV(s) and next iter's fence -> gap >= QK+SM
      if (s + 1 < hi2) loadV(s + 1);
    }
  }

  // epilogue: store UNNORMALIZED partial acc + l; combine kernel finishes.
  lsum += __shfl_xor(lsum, 32);  // lanes l and l+32 hold same q
  float* obase = h ? (float*)(ws + PART_OFF) : Out;
  float* lb = (float*)(ws + (h ? L1_OFF : L0_OFF)) + (size_t)b * S_LEN;
  if (lh == 0) lb[q0w + lq] = lsum;
  float* ob = obase + (size_t)(b * S_LEN + q0w + lq) * DV;
#pragma unroll
  for (int dt = 0; dt < 4; ++dt)
#pragma unroll
    for (int g = 0; g < 4; ++g) {
      f32x4 v = {oacc[dt][g * 4 + 0], oacc[dt][g * 4 + 1],
                 oacc[dt][g * 4 + 2], oacc[dt][g * 4 + 3]};
      *(f32x4*)(ob + dt * 32 + g * 8 + 4 * lh) = v;
    }
}

// Combine: Out = (Out + P1) / (l0 + l1). 2048 blocks x 256 threads x 8 floats.
// XCD-remapped: bid&7 = XCD, b = (bid&7)+8*((bid>>3)&1) matches fa_main_wave's
// batch->XCD mapping, so each XCD combines its own partials (L2-resident).
__global__ __launch_bounds__(256)
void fa_combine(float* __restrict__ Out, const char* __restrict__ ws) {
  const float* P1 = (const float*)(ws + PART_OFF);
  const float* L0 = (const float*)(ws + L0_OFF);
  const float* L1 = (const float*)(ws + L1_OFF);
  const int bid = blockIdx.x;
  const int b = (bid & 7) + 8 * ((bid >> 3) & 1);
  const int chunk = bid >> 4;  // [0,128) chunks of 2048 floats per batch
  const int base = b * (S_LEN * DV) + chunk * 2048 + threadIdx.x * 8;
  const int q = base >> 7;  // global row in [0, 16*2048)
  float inv = 1.0f / (L0[q] + L1[q]);
  f32x4 a0 = *(const f32x4*)(Out + base);
  f32x4 a1 = *(const f32x4*)(P1 + base);
  f32x4 b0 = *(const f32x4*)(Out + base + 4);
  f32x4 b1 = *(const f32x4*)(P1 + base + 4);
  *(f32x4*)(Out + base)     = (a0 + a1) * inv;
  *(f32x4*)(Out + base + 4) = (b0 + b1) * inv;
}

// ---------------------------------------------------------------------------
// Fallback (ws too small for split buffers): verified single-pass kernel,
// in-kernel convert, self-contained (no ws layout dependence).
// ---------------------------------------------------------------------------
#define LDP 72
__global__ __launch_bounds__(256)
void fa_fallback(const float* __restrict__ Q, const float* __restrict__ K,
                 const float* __restrict__ V, float* __restrict__ Out) {
  __shared__ __align__(16) short lds_k[BN * 136];
  __shared__ __align__(16) short lds_vt[DV * 72];
  __shared__ __align__(16) short lds_p[4 * 16 * LDP];

  const int bid = blockIdx.x;
  const int b = bid >> 5, t = bid & 31;
  const int q0 = t * 64;
  const int tid = threadIdx.x;
  const int wv = tid >> 6, ln = tid & 63;
  const int c = ln & 15, qd = ln >> 4;
  const float scale2 = 0.12751741f;
  const int qg = q0 + wv * 16 + c;

  bf16x8 qf[4];
  {
    const float* qrow = Q + (size_t)(b * S_LEN + qg) * DK + qd * 8;
#pragma unroll
    for (int t4 = 0; t4 < 4; ++t4) {
      float4 x = *(const float4*)(qrow + t4 * 32);
      float4 y = *(const float4*)(qrow + t4 * 32 + 4);
      s16x8 f;
      f[0] = f2bf(x.x * scale2); f[1] = f2bf(x.y * scale2);
      f[2] = f2bf(x.z * scale2); f[3] = f2bf(x.w * scale2);
      f[4] = f2bf(y.x * scale2); f[5] = f2bf(y.y * scale2);
      f[6] = f2bf(y.z * scale2); f[7] = f2bf(y.w * scale2);
      qf[t4] = __builtin_bit_cast(bf16x8, f);
    }
  }
  f32x4 oacc[8];
#pragma unroll
  for (int i = 0; i < 8; ++i) oacc[i] = f32x4{0.f, 0.f, 0.f, 0.f};
  float m_i = -1e30f, l_i = 0.f;
  const float* kbb = K + (size_t)b * S_LEN * DK;
  const float* vbb = V + (size_t)b * S_LEN * DV;
  short* pb = &lds_p[wv * 16 * LDP];

  for (int kt = 0; kt <= t; ++kt) {
    const int kv0 = kt * BN;
    __syncthreads();
    {
      const float* kb = kbb + (size_t)kv0 * DK;
#pragma unroll
      for (int it = 0; it < 8; ++it) {
        int flat = it * 256 + tid;
        int r = flat >> 5, d4 = flat & 31;
        float4 x = *(const float4*)(kb + r * DK + d4 * 4);
        s16x4 s;
        s[0] = f2bf(x.x); s[1] = f2bf(x.y); s[2] = f2bf(x.z); s[3] = f2bf(x.w);
        *(s16x4*)&lds_k[r * 136 + d4 * 4] = s;
      }
      const float* vb = vbb + (size_t)kv0 * DV;
#pragma unroll
      for (int it = 0; it < 8; ++it) {
        int flat = it * 256 + tid;
        int d = flat & 127, r0 = (flat >> 7) << 2;
        s16x4 s;
        s[0] = f2bf(vb[(r0 + 0) * DV + d]);
        s[1] = f2bf(vb[(r0 + 1) * DV + d]);
        s[2] = f2bf(vb[(r0 + 2) * DV + d]);
        s[3] = f2bf(vb[(r0 + 3) * DV + d]);
        *(s16x4*)&lds_vt[d * 72 + r0] = s;
      }
    }
    __syncthreads();
    f32x4 st[4];
#pragma unroll
    for (int cb = 0; cb < 4; ++cb) {
      f32x4 acc = f32x4{0.f, 0.f, 0.f, 0.f};
      const short* kr = &lds_k[(cb * 16 + c) * 136 + qd * 8];
#pragma unroll
      for (int t4 = 0; t4 < 4; ++t4)
        acc = __builtin_amdgcn_mfma_f32_16x16x32_bf16(lds8(kr + t4 * 32), qf[t4], acc, 0, 0, 0);
      st[cb] = acc;
    }
    if (kt == t) {
#pragma unroll
      for (int cb = 0; cb < 4; ++cb)
#pragma unroll
        for (int r = 0; r < 4; ++r)
          if (cb * 16 + qd * 4 + r > wv * 16 + c) st[cb][r] = -1e30f;
    }
    float tmax = -1e30f;
#pragma unroll
    for (int cb = 0; cb < 4; ++cb)
#pragma unroll
      for (int r = 0; r < 4; ++r) tmax = fmaxf(tmax, st[cb][r]);
    tmax = fmaxf(tmax, __shfl_xor(tmax, 16));
    tmax = fmaxf(tmax, __shfl_xor(tmax, 32));
    float mn = fmaxf(m_i, tmax);
    float al = __builtin_amdgcn_exp2f(m_i - mn);
    m_i = mn;
    float tsum = 0.f;
#pragma unroll
    for (int cb = 0; cb < 4; ++cb) {
      s16x4 pk;
#pragma unroll
      for (int r = 0; r < 4; ++r) {
        float p = __builtin_amdgcn_exp2f(st[cb][r] - m_i);
        tsum += p;
        pk[r] = f2bf(p);
      }
      *(s16x4*)&pb[c * LDP + cb * 16 + qd * 4] = pk;
    }
    tsum += __shfl_xor(tsum, 16);
    tsum += __shfl_xor(tsum, 32);
    l_i = l_i * al + tsum;
#pragma unroll
    for (int i = 0; i < 8; ++i)
#pragma unroll
      for (int r = 0; r < 4; ++r) oacc[i][r] *= al;
#pragma unroll
    for (int t2 = 0; t2 < 2; ++t2) {
      bf16x8 pf = lds8(&pb[c * LDP + t2 * 32 + qd * 8]);
#pragma unroll
      for (int cb2 = 0; cb2 < 8; ++cb2) {
        bf16x8 vf = lds8(&lds_vt[(cb2 * 16 + c) * 72 + t2 * 32 + qd * 8]);
        oacc[cb2] = __builtin_amdgcn_mfma_f32_16x16x32_bf16(vf, pf, oacc[cb2], 0, 0, 0);
      }
    }
  }
  float inv = 1.0f / l_i;
  float* ob = Out + (size_t)(b * S_LEN + qg) * DV;
#pragma unroll
  for (int cb2 = 0; cb2 < 8; ++cb2) {
    f32x4 v = oacc[cb2] * inv;
    *(f32x4*)(ob + cb2 * 16 + qd * 4) = v;
  }
}

extern "C" void kernel_launch(void* const* d_in, const int* in_sizes, int n_in,
                              void* d_out, int out_size, void* d_ws, size_t ws_size,
                              hipStream_t stream) {
  (void)in_sizes; (void)n_in; (void)out_size;
  const float* Q = (const float*)d_in[0];
  const float* K = (const float*)d_in[1];
  const float* V = (const float*)d_in[2];
  float* O = (float*)d_out;
  if (ws_size >= WS_NEED_SPLIT) {
    fa_convert<<<dim3(1024), dim3(256), 0, stream>>>(K, V, (char*)d_ws);
    fa_main_wave<<<dim3(512), dim3(256), 0, stream>>>(Q, (char*)d_ws, O);
    fa_combine<<<dim3(2048), dim3(256), 0, stream>>>(O, (const char*)d_ws);
  } else {
    fa_fallback<<<dim3(512), dim3(256), 0, stream>>>(Q, K, V, O);
  }
}